// Round 8
// baseline (364.886 us; speedup 1.0000x reference)
//
#include <hip/hip_runtime.h>

typedef __attribute__((ext_vector_type(8))) __bf16 bf16x8;
typedef __attribute__((ext_vector_type(4))) float f32x4;
typedef __attribute__((ext_vector_type(4))) unsigned int u32x4;

__device__ __forceinline__ unsigned short f2bf(float f){
    unsigned int x = __builtin_bit_cast(unsigned int, f);
    x += 0x7FFFu + ((x >> 16) & 1u);
    return (unsigned short)(x >> 16);
}
__device__ __forceinline__ unsigned int pk2(float a, float b){
    return (unsigned int)f2bf(a) | ((unsigned int)f2bf(b) << 16);
}
// HW packed conversion: low16 = bf16(a), high16 = bf16(b), RNE
__device__ __forceinline__ unsigned int cvtpk(float a, float b){
    unsigned int r;
    asm("v_cvt_pk_bf16_f32 %0, %1, %2" : "=v"(r) : "v"(a), "v"(b));
    return r;
}
__device__ __forceinline__ unsigned short cvt1(float a){
    return (unsigned short)(cvtpk(a, a) & 0xFFFFu);
}
__device__ __forceinline__ bf16x8 ldfrag(const unsigned short* p){
    u32x4 v = *reinterpret_cast<const u32x4*>(p);
    return __builtin_bit_cast(bf16x8, v);
}
__device__ __forceinline__ f32x4 mfma_bf16(bf16x8 a, bf16x8 b, f32x4 c){
    return __builtin_amdgcn_mfma_f32_16x16x32_bf16(a, b, c, 0, 0, 0);
}

// workspace (shorts): w1f 54*512 = 27648 | w2f 18*512 = 9216 | b1p (float[288])
#define W1F_SH 27648
#define W2F_SH 9216

// ---------------- Kernel 0: weight prep (fragment-major bf16; Q rows pre-scaled) -----
__global__ __launch_bounds__(256) void k_prep(const float* __restrict__ w1,
                                              const float* __restrict__ b1,
                                              const float* __restrict__ w2,
                                              unsigned short* __restrict__ w1f,
                                              unsigned short* __restrict__ w2f,
                                              float* __restrict__ b1p)
{
    const float SCALE = 0.17677669529663687f;   // 1/sqrt(32)
    int i = blockIdx.x * 256 + threadIdx.x;
    if (i < 3456){
        int f = i >> 6, lane = i & 63;
        int n = f / 3, ks = f - n * 3;
        int l15 = lane & 15, qd = lane >> 4;
        int rp = n * 16 + l15;
        int c = rp / 96, rem = rp - c * 96;
        float s = (c == 0) ? SCALE : 1.0f;
        const float* src = w1 + (size_t)(3 * rem + c) * 96 + ks * 32 + qd * 8;
        f32x4 v0 = *reinterpret_cast<const f32x4*>(src);
        f32x4 v1 = *reinterpret_cast<const f32x4*>(src + 4);
        u32x4 p;
        p[0] = pk2(v0[0] * s, v0[1] * s); p[1] = pk2(v0[2] * s, v0[3] * s);
        p[2] = pk2(v1[0] * s, v1[1] * s); p[3] = pk2(v1[2] * s, v1[3] * s);
        *reinterpret_cast<u32x4*>(w1f + (size_t)f * 512 + lane * 8) = p;
    } else if (i < 4608){
        int j = i - 3456;
        int f = j >> 6, lane = j & 63;
        int n = f / 3, ks = f - n * 3;
        int l15 = lane & 15, qd = lane >> 4;
        const float* src = w2 + (size_t)(n * 16 + l15) * 96 + ks * 32 + qd * 8;
        f32x4 v0 = *reinterpret_cast<const f32x4*>(src);
        f32x4 v1 = *reinterpret_cast<const f32x4*>(src + 4);
        u32x4 p;
        p[0] = pk2(v0[0], v0[1]); p[1] = pk2(v0[2], v0[3]);
        p[2] = pk2(v1[0], v1[1]); p[3] = pk2(v1[2], v1[3]);
        *reinterpret_cast<u32x4*>(w2f + (size_t)f * 512 + lane * 8) = p;
    } else if (i < 4896){
        int rp = i - 4608;
        int c = rp / 96, rem = rp - c * 96;
        b1p[rp] = b1[3 * rem + c] * ((c == 0) ? SCALE : 1.0f);
    }
}

// ---------------- per-window device pieces (verbatim logic from round 7) -------------

__device__ __forceinline__ void load_x_raw(const float* __restrict__ x, int b, int wy, int wx,
                                           int wave, int l15, int qd, f32x4* xv)
{
    int pos = wave * 16 + l15;                   // rows >=49 load in-bounds garbage
    int iy = pos / 7, ix = pos - iy * 7;
    int h = wy * 7 + iy + 4; if (h >= 56) h -= 56;   // undo roll(-4)
    int w = wx * 7 + ix + 4; if (w >= 56) w -= 56;
    const float* xr = x + ((size_t)b * 3136 + h * 56 + w) * 96 + qd * 8;
    xv[0] = *reinterpret_cast<const f32x4*>(xr);
    xv[1] = *reinterpret_cast<const f32x4*>(xr + 4);
    xv[2] = *reinterpret_cast<const f32x4*>(xr + 32);
    xv[3] = *reinterpret_cast<const f32x4*>(xr + 36);
    xv[4] = *reinterpret_cast<const f32x4*>(xr + 64);
    xv[5] = *reinterpret_cast<const f32x4*>(xr + 68);
}

__device__ __forceinline__ void compute_A(const f32x4* xv,
    const unsigned short* __restrict__ w1f, const float* __restrict__ b1p,
    unsigned short* Kr, unsigned short* Vt,
    int wave, int lane, int l15, int qd, int s0, int s1, bf16x8* bQf)
{
    u32x4 t;
    t[0] = cvtpk(xv[0][0], xv[0][1]); t[1] = cvtpk(xv[0][2], xv[0][3]);
    t[2] = cvtpk(xv[1][0], xv[1][1]); t[3] = cvtpk(xv[1][2], xv[1][3]);
    bf16x8 aX0 = __builtin_bit_cast(bf16x8, t);
    t[0] = cvtpk(xv[2][0], xv[2][1]); t[1] = cvtpk(xv[2][2], xv[2][3]);
    t[2] = cvtpk(xv[3][0], xv[3][1]); t[3] = cvtpk(xv[3][2], xv[3][3]);
    bf16x8 aX1 = __builtin_bit_cast(bf16x8, t);
    t[0] = cvtpk(xv[4][0], xv[4][1]); t[1] = cvtpk(xv[4][2], xv[4][3]);
    t[2] = cvtpk(xv[5][0], xv[5][1]); t[3] = cvtpk(xv[5][2], xv[5][3]);
    bf16x8 aX2 = __builtin_bit_cast(bf16x8, t);

    // group Q (swapped operands): accQT[e'][pos]
    unsigned int Qw[12];
#pragma unroll
    for (int qt = 0; qt < 6; ++qt){
        const unsigned short* wf = w1f + (size_t)(qt * 3) * 512 + lane * 8;
        f32x4 a = {0.f, 0.f, 0.f, 0.f};
        a = mfma_bf16(ldfrag(wf),        aX0, a);
        a = mfma_bf16(ldfrag(wf + 512),  aX1, a);
        a = mfma_bf16(ldfrag(wf + 1024), aX2, a);
        f32x4 bq = *reinterpret_cast<const f32x4*>(b1p + qt * 16 + qd * 4);
        Qw[qt * 2]     = cvtpk(a[0] + bq[0], a[1] + bq[1]);
        Qw[qt * 2 + 1] = cvtpk(a[2] + bq[2], a[3] + bq[3]);
    }
    // repack tile-pairs -> B-frag per head: lane holds Q[q=l15][eh=qd*8..+7]
#pragma unroll
    for (int H = 0; H < 3; ++H){
        u32x4 qw; unsigned int lo, hi;
        lo = (unsigned)__shfl((int)Qw[(2*H)*2],     s0, 64);
        hi = (unsigned)__shfl((int)Qw[(2*H+1)*2],   s0, 64); qw[0] = (qd & 2) ? hi : lo;
        lo = (unsigned)__shfl((int)Qw[(2*H)*2+1],   s0, 64);
        hi = (unsigned)__shfl((int)Qw[(2*H+1)*2+1], s0, 64); qw[1] = (qd & 2) ? hi : lo;
        lo = (unsigned)__shfl((int)Qw[(2*H)*2],     s1, 64);
        hi = (unsigned)__shfl((int)Qw[(2*H+1)*2],   s1, 64); qw[2] = (qd & 2) ? hi : lo;
        lo = (unsigned)__shfl((int)Qw[(2*H)*2+1],   s1, 64);
        hi = (unsigned)__shfl((int)Qw[(2*H+1)*2+1], s1, 64); qw[3] = (qd & 2) ? hi : lo;
        bQf[H] = __builtin_bit_cast(bf16x8, qw);
    }
    // group K -> swizzled LDS [H][pos][32]
#pragma unroll
    for (int n = 0; n < 6; ++n){
        const unsigned short* wf = w1f + (size_t)((6 + n) * 3) * 512 + lane * 8;
        f32x4 a = {0.f, 0.f, 0.f, 0.f};
        a = mfma_bf16(aX0, ldfrag(wf),        a);
        a = mfma_bf16(aX1, ldfrag(wf + 512),  a);
        a = mfma_bf16(aX2, ldfrag(wf + 1024), a);
        float bb = b1p[(6 + n) * 16 + l15];
        int H = n >> 1;
        int eh = ((n & 1) << 4) + l15;
        int ch = eh >> 3;
#pragma unroll
        for (int r = 0; r < 4; ++r){
            int p = wave * 16 + qd * 4 + r;
            int chs = ch ^ ((p >> 1) & 3);
            Kr[H * 2048 + p * 32 + chs * 8 + (eh & 7)] = cvt1(a[r] + bb);
        }
    }
    // group V -> Vt [H][eh][pos] (paired b32 writes)
#pragma unroll
    for (int n = 0; n < 6; ++n){
        const unsigned short* wf = w1f + (size_t)((12 + n) * 3) * 512 + lane * 8;
        f32x4 a = {0.f, 0.f, 0.f, 0.f};
        a = mfma_bf16(aX0, ldfrag(wf),        a);
        a = mfma_bf16(aX1, ldfrag(wf + 512),  a);
        a = mfma_bf16(aX2, ldfrag(wf + 1024), a);
        float bb = b1p[(12 + n) * 16 + l15];
        int H = n >> 1;
        int eh = ((n & 1) << 4) + l15;
        int p0 = wave * 16 + qd * 4;
#pragma unroll
        for (int rp = 0; rp < 2; ++rp)
            *reinterpret_cast<unsigned int*>(&Vt[(H * 32 + eh) * 72 + p0 + 2 * rp])
                = cvtpk(a[2 * rp] + bb, a[2 * rp + 1] + bb);
    }
}

__device__ __forceinline__ void phase_B(const unsigned short* Kr, const unsigned short* Vt,
    const bf16x8* bQf, int wy, int wx, int wave, int l15, int qd, int s0, int s1, int chq,
    bf16x8* aO)
{
    const bool rowm = (wy == 7), colm = (wx == 7);
    const float NEGINF = -__builtin_inff();
    // closed-form col-mask tables (bit = tn*4+r, col = tn*16+qd*4+r)
    const unsigned int m49 = (qd == 0) ? 0xE000u : 0xF000u;
    const unsigned int m28 = (qd == 3) ? 0xFFF0u : 0xFF00u;
    const unsigned int m7  = (qd & 2) ? ((qd & 1) ? 0x7C03u : 0x03E8u)
                                      : ((qd & 1) ? 0xE817u : 0x17C0u);
    const int qrow = wave * 16 + l15;
    const bool rhi = (qrow >= 28);
    const bool rc7 = ((qrow % 7) >= 4);
    // hoisted mask addends (head-independent): 0 or -inf
    float madd[16];
#pragma unroll
    for (int bit = 0; bit < 16; ++bit){
        bool blocked = (((m49 >> bit) & 1u) != 0u)
            || (rowm && (rhi != (((m28 >> bit) & 1u) != 0u)))
            || (colm && (rc7 != (((m7 >> bit) & 1u) != 0u)));
        madd[bit] = blocked ? NEGINF : 0.f;
    }

    unsigned int Ow[12];
#pragma unroll
    for (int H = 0; H < 3; ++H){
        f32x4 S[4];
        __builtin_amdgcn_s_setprio(1);
#pragma unroll
        for (int tn = 0; tn < 4; ++tn){
            bf16x8 aK = ldfrag(Kr + H * 2048 + (tn * 16 + l15) * 32 + chq * 8);
            f32x4 z = {0.f, 0.f, 0.f, 0.f};
            S[tn] = mfma_bf16(aK, bQf[H], z);    // S^T[k=tn*16+qd*4+r][q=l15]
        }
        __builtin_amdgcn_s_setprio(0);
        float v[16];
#pragma unroll
        for (int tn = 0; tn < 4; ++tn)
#pragma unroll
            for (int r = 0; r < 4; ++r)
                v[tn * 4 + r] = S[tn][r] + madd[tn * 4 + r];
        // max tree (max3-fusable, depth 3)
        float a0 = fmaxf(fmaxf(v[0], v[1]),  v[2]);
        float a1 = fmaxf(fmaxf(v[3], v[4]),  v[5]);
        float a2 = fmaxf(fmaxf(v[6], v[7]),  v[8]);
        float a3 = fmaxf(fmaxf(v[9], v[10]), v[11]);
        float a4 = fmaxf(fmaxf(v[12], v[13]), v[14]);
        float mx = fmaxf(fmaxf(fmaxf(a0, a1), a2), fmaxf(fmaxf(a3, a4), v[15]));
        mx = fmaxf(mx, __shfl_xor(mx, 16, 64));
        mx = fmaxf(mx, __shfl_xor(mx, 32, 64));
        float e[16];
#pragma unroll
        for (int i = 0; i < 16; ++i) e[i] = exp2f((v[i] - mx) * 1.4426950408889634f);
        // sum tree (depth 4)
        float t8[8];
#pragma unroll
        for (int i = 0; i < 8; ++i) t8[i] = e[2 * i] + e[2 * i + 1];
        float t4[4];
#pragma unroll
        for (int i = 0; i < 4; ++i) t4[i] = t8[2 * i] + t8[2 * i + 1];
        float sum = (t4[0] + t4[1]) + (t4[2] + t4[3]);
        sum += __shfl_xor(sum, 16, 64);
        sum += __shfl_xor(sum, 32, 64);
        float inv = 1.f / sum;                   // per-q, lane-local

        unsigned int pkv[8];
#pragma unroll
        for (int tn = 0; tn < 4; ++tn){
            pkv[tn * 2]     = cvtpk(e[tn * 4 + 0], e[tn * 4 + 1]);
            pkv[tn * 2 + 1] = cvtpk(e[tn * 4 + 2], e[tn * 4 + 3]);
        }
        bf16x8 pF[2];                            // B-frag: P[q=l15][k=kt*32+qd*8..]
#pragma unroll
        for (int kt = 0; kt < 2; ++kt){
            u32x4 aw;
#pragma unroll
            for (int w4 = 0; w4 < 4; ++w4){
                int srcl = (w4 < 2) ? s0 : s1;
                unsigned int lo = (unsigned)__shfl((int)pkv[(2 * kt) * 2 + (w4 & 1)], srcl, 64);
                unsigned int hi = (unsigned)__shfl((int)pkv[(2 * kt + 1) * 2 + (w4 & 1)], srcl, 64);
                aw[w4] = (qd & 2) ? hi : lo;
            }
            pF[kt] = __builtin_bit_cast(bf16x8, aw);
        }
        // O^T: rows = eh (qd*4+r per et), cols = q (l15)
#pragma unroll
        for (int et = 0; et < 2; ++et){
            f32x4 o = {0.f, 0.f, 0.f, 0.f};
            __builtin_amdgcn_s_setprio(1);
#pragma unroll
            for (int kt = 0; kt < 2; ++kt){
                bf16x8 aV = ldfrag(Vt + (H * 32 + et * 16 + l15) * 72 + kt * 32 + qd * 8);
                o = mfma_bf16(aV, pF[kt], o);
            }
            __builtin_amdgcn_s_setprio(0);
            Ow[(H * 2 + et) * 2]     = cvtpk(o[0] * inv, o[1] * inv);
            Ow[(H * 2 + et) * 2 + 1] = cvtpk(o[2] * inv, o[3] * inv);
        }
    }
    // repack O tile-pairs -> A-frags: lane holds O[row=l15][ch=c*32+qd*8..+7]
#pragma unroll
    for (int c = 0; c < 3; ++c){
        u32x4 qw; unsigned int lo, hi;
        lo = (unsigned)__shfl((int)Ow[(2*c)*2],     s0, 64);
        hi = (unsigned)__shfl((int)Ow[(2*c+1)*2],   s0, 64); qw[0] = (qd & 2) ? hi : lo;
        lo = (unsigned)__shfl((int)Ow[(2*c)*2+1],   s0, 64);
        hi = (unsigned)__shfl((int)Ow[(2*c+1)*2+1], s0, 64); qw[1] = (qd & 2) ? hi : lo;
        lo = (unsigned)__shfl((int)Ow[(2*c)*2],     s1, 64);
        hi = (unsigned)__shfl((int)Ow[(2*c+1)*2],   s1, 64); qw[2] = (qd & 2) ? hi : lo;
        lo = (unsigned)__shfl((int)Ow[(2*c)*2+1],   s1, 64);
        hi = (unsigned)__shfl((int)Ow[(2*c+1)*2+1], s1, 64); qw[3] = (qd & 2) ? hi : lo;
        aO[c] = __builtin_bit_cast(bf16x8, qw);
    }
}

__device__ __forceinline__ void phase_C(const bf16x8* aO,
    const unsigned short* __restrict__ w2f, const float* __restrict__ b2,
    float* __restrict__ out, int b, int wy, int wx, int wave, int lane, int l15, int qd)
{
    f32x4 acc2[6];
#pragma unroll
    for (int n = 0; n < 6; ++n){
        const unsigned short* wf = w2f + (size_t)(n * 3) * 512 + lane * 8;
        f32x4 a = {0.f, 0.f, 0.f, 0.f};
        a = mfma_bf16(aO[0], ldfrag(wf),        a);
        a = mfma_bf16(aO[1], ldfrag(wf + 512),  a);
        a = mfma_bf16(aO[2], ldfrag(wf + 1024), a);
        acc2[n] = a;
    }
    float bb2[6];
#pragma unroll
    for (int n = 0; n < 6; ++n) bb2[n] = b2[n * 16 + l15];
#pragma unroll
    for (int r = 0; r < 4; ++r){
        int row = wave * 16 + qd * 4 + r;
        int iy = row / 7, ix = row - iy * 7;
        int h = wy * 7 + iy + 3; if (h >= 56) h -= 56;   // roll +3
        int w = wx * 7 + ix + 3; if (w >= 56) w -= 56;
        float* dst = out + ((size_t)b * 3136 + h * 56 + w) * 96 + l15;
        if (row < 49){
#pragma unroll
            for (int n = 0; n < 6; ++n)
                dst[n * 16] = acc2[n][r] + bb2[n];
        }
    }
}

// ---------------- Kernel 1: 2-window software-pipelined fused kernel ----------------
// Per block: windows w0 = 2*bid (wx even) and w1 = w0+1 (same b, wy).
// LDS: 2 buffers x (K 12288 B + Vt 13824 B) = 52224 B -> 3 blocks/CU.
// Region between barriers mixes B(w0) [LDS0 reads + softmax] with A(w1)
// [VMEM loads + MFMA + LDS1 writes] + C(w0) -> uncorrelated stall mix.
__global__ __launch_bounds__(256, 3) void k_fused(const float* __restrict__ x,
                                                  const unsigned short* __restrict__ w1f,
                                                  const float* __restrict__ b1p,
                                                  const unsigned short* __restrict__ w2f,
                                                  const float* __restrict__ b2,
                                                  float* __restrict__ out)
{
    __shared__ __align__(16) unsigned short smem[2][13056];   // 52224 B

    const int tid = threadIdx.x;
    const int w0 = blockIdx.x * 2;
    const int b = w0 >> 6, wy = (w0 >> 3) & 7, wx0 = w0 & 7, wx1 = wx0 + 1;
    const int wave = tid >> 6, lane = tid & 63;
    const int l15 = lane & 15, qd = lane >> 4;
    const int s0 = (qd & 1) * 32 + l15;
    const int s1 = s0 + 16;
    const int chq = qd ^ ((l15 >> 1) & 3);

    // ---- A(w0) ----
    f32x4 xv0[6];
    load_x_raw(x, b, wy, wx0, wave, l15, qd, xv0);
    bf16x8 bQf0[3];
    compute_A(xv0, w1f, b1p, smem[0], smem[0] + 6144, wave, lane, l15, qd, s0, s1, bQf0);
    __syncthreads();

    // ---- [x(w1) issue] B(w0) || A(w1) ; C(w0) ----
    f32x4 xv1[6];
    load_x_raw(x, b, wy, wx1, wave, l15, qd, xv1);   // VMEM issued before B(w0)
    bf16x8 aO0[3];
    phase_B(smem[0], smem[0] + 6144, bQf0, wy, wx0, wave, l15, qd, s0, s1, chq, aO0);
    bf16x8 bQf1[3];
    compute_A(xv1, w1f, b1p, smem[1], smem[1] + 6144, wave, lane, l15, qd, s0, s1, bQf1);
    phase_C(aO0, w2f, b2, out, b, wy, wx0, wave, lane, l15, qd);
    __syncthreads();

    // ---- B(w1) ; C(w1) ----
    bf16x8 aO1[3];
    phase_B(smem[1], smem[1] + 6144, bQf1, wy, wx1, wave, l15, qd, s0, s1, chq, aO1);
    phase_C(aO1, w2f, b2, out, b, wy, wx1, wave, lane, l15, qd);
}

extern "C" void kernel_launch(void* const* d_in, const int* in_sizes, int n_in,
                              void* d_out, int out_size, void* d_ws, size_t ws_size,
                              hipStream_t stream)
{
    const float* x  = (const float*)d_in[0];
    const float* w1 = (const float*)d_in[1];
    const float* b1 = (const float*)d_in[2];
    const float* w2 = (const float*)d_in[3];
    const float* b2 = (const float*)d_in[4];
    float* out = (float*)d_out;

    unsigned short* w1f = (unsigned short*)d_ws;
    unsigned short* w2f = w1f + W1F_SH;
    float* b1p = (float*)(w2f + W2F_SH);

    hipLaunchKernelGGL(k_prep,  dim3(20),   dim3(256), 0, stream, w1, b1, w2, w1f, w2f, b1p);
    hipLaunchKernelGGL(k_fused, dim3(4096), dim3(256), 0, stream, x, w1f, b1p, w2f, b2, out);
}